// Round 8
// baseline (235.740 us; speedup 1.0000x reference)
//
#include <hip/hip_runtime.h>

typedef unsigned short ushort_t;
typedef __attribute__((ext_vector_type(8))) short bf16x8;     // 8 bf16 in 4 VGPRs
typedef __attribute__((ext_vector_type(4))) float f32x4;
typedef __attribute__((ext_vector_type(16))) float f32x16;

__device__ __forceinline__ unsigned short f2bf(float f) {
    union { float f; unsigned u; } v; v.f = f;
    unsigned r = v.u + 0x7FFFu + ((v.u >> 16) & 1u);   // RNE
    return (unsigned short)(r >> 16);
}

// ================= weight prep =================
// W1eff[n,p] = sum cw[dr,dc]*fc1_w[n,(pr-dr)*26+(pc-dc)]   (conv folded into fc1), [512,832] pad
// W2 = bf16(fc2_w) [512,512];  W3 = bf16(out_w) padded to [16,512]
__global__ __launch_bounds__(256) void prep_w(const float* __restrict__ fc1_w,
                                              const float* __restrict__ cw,
                                              const float* __restrict__ fc2_w,
                                              const float* __restrict__ out_w,
                                              ushort_t* __restrict__ W1,
                                              ushort_t* __restrict__ W2,
                                              ushort_t* __restrict__ W3) {
    const int idx = blockIdx.x * 256 + threadIdx.x;
    if (idx < 512 * 832) {
        int n = idx / 832, p = idx % 832;
        float acc = 0.f;
        if (p < 784) {
            int pr = p / 28, pc = p % 28;
#pragma unroll
            for (int dr = 0; dr < 3; ++dr) {
                int r = pr - dr;
                if (r < 0 || r >= 26) continue;
#pragma unroll
                for (int dc = 0; dc < 3; ++dc) {
                    int col = pc - dc;
                    if (col < 0 || col >= 26) continue;
                    acc += cw[dr * 3 + dc] * fc1_w[n * 676 + r * 26 + col];
                }
            }
        }
        W1[idx] = f2bf(acc);
    }
    if (idx < 512 * 512) W2[idx] = f2bf(fc2_w[idx]);
    if (idx < 16 * 512)  W3[idx] = (idx < 10 * 512) ? f2bf(out_w[idx]) : (ushort_t)0;
}

// ================= fully-fused network, v2 =================
// 256 blocks x 128 batch rows (two 64-row halves), 512 threads (8 waves), 1 block/CU.
// W is NOT staged through LDS: each wave reads its 64-n-row W slice directly from global
// as B-fragments (identical rows across all blocks -> L2/L1 resident). x is nontemporal
// (streaming; don't evict W from L2), cast to bf16 in regs, staged into 16KB LDS with a
// one-step prefetch. h1/h2 [128][512] live in a 128KB LDS tile; out stored directly.
__global__ __launch_bounds__(512, 2) void mega2(const float* __restrict__ x,
                                                const ushort_t* __restrict__ W1,
                                                const ushort_t* __restrict__ W2,
                                                const ushort_t* __restrict__ W3,
                                                const float* __restrict__ b1,
                                                const float* __restrict__ b2,
                                                const float* __restrict__ ob,
                                                float* __restrict__ out) {
    extern __shared__ ushort_t smem[];
    ushort_t* xs = smem;                 // [2][64][64]  16 KB  x-chunks (bf16, seg-swizzled)
    ushort_t* hs = smem + 8192;          // [128][512]  128 KB  h1 / h2 tile

    const int tid = threadIdx.x;
    const int wave = tid >> 6, lane = tid & 63;
    const int r32 = lane & 31, khalf = lane >> 5;
    const int xrow = tid >> 3, xoct = tid & 7;          // x staging: 64 rows x 8 octs
    const int m0 = blockIdx.x * 128;

    f32x16 acc[2][2][2];                                // [mh][i][j]
#pragma unroll
    for (int a = 0; a < 2; ++a)
#pragma unroll
        for (int i = 0; i < 2; ++i)
#pragma unroll
            for (int j = 0; j < 2; ++j)
#pragma unroll
                for (int e = 0; e < 16; ++e) acc[a][i][j][e] = 0.f;

    // ---- x prefetch (nontemporal), one K-step ahead ----
    f32x4 xv0[2], xv1[2];
    auto load_x = [&](int ks) {
        const int gc = ks * 64 + xoct * 8;
#pragma unroll
        for (int mh = 0; mh < 2; ++mh) {
            if (gc < 784) {
                const f32x4* p = (const f32x4*)&x[(size_t)(m0 + mh * 64 + xrow) * 784 + gc];
                xv0[mh] = __builtin_nontemporal_load(p);
                xv1[mh] = __builtin_nontemporal_load(p + 1);
            } else {
                xv0[mh] = (f32x4){0.f, 0.f, 0.f, 0.f};
                xv1[mh] = (f32x4){0.f, 0.f, 0.f, 0.f};
            }
        }
    };
    load_x(0);

    // ---------------- phase 1: K = 832, 13 steps of BK=64 ----------------
    for (int ks = 0; ks < 13; ++ks) {
        // cast prefetched x -> xs (seg-swizzled so fragment reads are conflict-light)
#pragma unroll
        for (int mh = 0; mh < 2; ++mh) {
            bf16x8 xv;
            xv[0] = (short)f2bf(xv0[mh].x); xv[1] = (short)f2bf(xv0[mh].y);
            xv[2] = (short)f2bf(xv0[mh].z); xv[3] = (short)f2bf(xv0[mh].w);
            xv[4] = (short)f2bf(xv1[mh].x); xv[5] = (short)f2bf(xv1[mh].y);
            xv[6] = (short)f2bf(xv1[mh].z); xv[7] = (short)f2bf(xv1[mh].w);
            *(bf16x8*)&xs[mh * 4096 + xrow * 64 + ((xoct ^ (xrow & 7)) * 8)] = xv;
        }
        __syncthreads();
        if (ks < 12) load_x(ks + 1);                    // issue next x loads under the MFMAs
        const int k0 = ks * 64;
#pragma unroll
        for (int ksub = 0; ksub < 4; ++ksub) {
            const int q = 2 * ksub + khalf;
            bf16x8 bw[2], af[2][2];
#pragma unroll
            for (int j = 0; j < 2; ++j)
                bw[j] = *(const bf16x8*)&W1[(size_t)(wave * 64 + j * 32 + r32) * 832 + k0 + q * 8];
#pragma unroll
            for (int mh = 0; mh < 2; ++mh)
#pragma unroll
                for (int i = 0; i < 2; ++i) {
                    const int mr = i * 32 + r32;
                    af[mh][i] = *(const bf16x8*)&xs[mh * 4096 + mr * 64 + ((q ^ (mr & 7)) * 8)];
                }
#pragma unroll
            for (int mh = 0; mh < 2; ++mh)
#pragma unroll
                for (int i = 0; i < 2; ++i)
#pragma unroll
                    for (int j = 0; j < 2; ++j)
                        acc[mh][i][j] = __builtin_amdgcn_mfma_f32_32x32x16_bf16(af[mh][i], bw[j], acc[mh][i][j], 0, 0, 0);
        }
        __syncthreads();
    }

    // ---- h1 = relu(acc + b1) -> hs (A-layout, seg' = seg ^ (m&7)) ----
#pragma unroll
    for (int j = 0; j < 2; ++j) {
        const int n = wave * 64 + j * 32 + r32;
        const float bb = b1[n];
        const int nseg = n >> 3, nrem = n & 7;
#pragma unroll
        for (int mh = 0; mh < 2; ++mh)
#pragma unroll
            for (int i = 0; i < 2; ++i)
#pragma unroll
                for (int reg = 0; reg < 16; ++reg) {
                    const int m = mh * 64 + i * 32 + 4 * khalf + (reg & 3) + 8 * (reg >> 2);
                    hs[m * 512 + ((nseg ^ (m & 7)) * 8) + nrem] = f2bf(fmaxf(acc[mh][i][j][reg] + bb, 0.f));
                }
    }
#pragma unroll
    for (int a = 0; a < 2; ++a)
#pragma unroll
        for (int i = 0; i < 2; ++i)
#pragma unroll
            for (int j = 0; j < 2; ++j)
#pragma unroll
                for (int e = 0; e < 16; ++e) acc[a][i][j][e] = 0.f;
    __syncthreads();

    // ---------------- phase 2: K = 512, 8 steps of BK=64, no barriers ----------------
    for (int ks = 0; ks < 8; ++ks) {
        const int k0 = ks * 64;
#pragma unroll
        for (int ksub = 0; ksub < 4; ++ksub) {
            const int q = 2 * ksub + khalf;
            const int hq = ks * 8 + q;                  // 16B-seg index within hs row (0..63)
            bf16x8 bw[2], af[2][2];
#pragma unroll
            for (int j = 0; j < 2; ++j)
                bw[j] = *(const bf16x8*)&W2[(size_t)(wave * 64 + j * 32 + r32) * 512 + k0 + q * 8];
#pragma unroll
            for (int mh = 0; mh < 2; ++mh)
#pragma unroll
                for (int i = 0; i < 2; ++i) {
                    const int m = mh * 64 + i * 32 + r32;
                    af[mh][i] = *(const bf16x8*)&hs[m * 512 + ((hq ^ (m & 7)) * 8)];
                }
#pragma unroll
            for (int mh = 0; mh < 2; ++mh)
#pragma unroll
                for (int i = 0; i < 2; ++i)
#pragma unroll
                    for (int j = 0; j < 2; ++j)
                        acc[mh][i][j] = __builtin_amdgcn_mfma_f32_32x32x16_bf16(af[mh][i], bw[j], acc[mh][i][j], 0, 0, 0);
        }
    }
    __syncthreads();                                    // all hs(h1) reads done

    // ---- h2 = relu(acc + b2) -> hs ----
#pragma unroll
    for (int j = 0; j < 2; ++j) {
        const int n = wave * 64 + j * 32 + r32;
        const float bb = b2[n];
        const int nseg = n >> 3, nrem = n & 7;
#pragma unroll
        for (int mh = 0; mh < 2; ++mh)
#pragma unroll
            for (int i = 0; i < 2; ++i)
#pragma unroll
                for (int reg = 0; reg < 16; ++reg) {
                    const int m = mh * 64 + i * 32 + 4 * khalf + (reg & 3) + 8 * (reg >> 2);
                    hs[m * 512 + ((nseg ^ (m & 7)) * 8) + nrem] = f2bf(fmaxf(acc[mh][i][j][reg] + bb, 0.f));
                }
    }
    __syncthreads();

    // ---------------- head: wave w -> rows [16w,16w+16), K=512, direct stores ----------------
    {
        const int quad = lane >> 4, l16 = lane & 15;
        const int row = wave * 16 + l16;
        f32x4 hacc = {0.f, 0.f, 0.f, 0.f};
#pragma unroll
        for (int ks = 0; ks < 16; ++ks) {
            const int seg = 4 * ks + quad;
            const bf16x8 a = *(const bf16x8*)&hs[row * 512 + ((seg ^ (row & 7)) * 8)];
            const bf16x8 b = *(const bf16x8*)&W3[l16 * 512 + ks * 32 + quad * 8];
            hacc = __builtin_amdgcn_mfma_f32_16x16x32_bf16(a, b, hacc, 0, 0, 0);
        }
        if (l16 < 10) {
            const float bb = ob[l16];
#pragma unroll
            for (int r = 0; r < 4; ++r)
                out[(size_t)(m0 + wave * 16 + quad * 4 + r) * 10 + l16] = hacc[r] + bb;
        }
    }
}

extern "C" void kernel_launch(void* const* d_in, const int* in_sizes, int n_in,
                              void* d_out, int out_size, void* d_ws, size_t ws_size,
                              hipStream_t stream) {
    const float* x      = (const float*)d_in[0];
    const float* conv_w = (const float*)d_in[1];
    const float* fc1_w  = (const float*)d_in[2];
    const float* fc1_b  = (const float*)d_in[3];
    const float* fc2_w  = (const float*)d_in[4];
    const float* fc2_b  = (const float*)d_in[5];
    const float* out_w  = (const float*)d_in[6];
    const float* out_b  = (const float*)d_in[7];
    float* out = (float*)d_out;

    // workspace: W1eff | W2 | W3 (≈1.4 MB total)
    ushort_t* W1 = (ushort_t*)d_ws;                    // 512*832
    ushort_t* W2 = W1 + 512 * 832;                     // 512*512
    ushort_t* W3 = W2 + 512 * 512;                     // 16*512

    prep_w<<<dim3(1664), 256, 0, stream>>>(fc1_w, conv_w, fc2_w, out_w, W1, W2, W3);

    // 256 blocks x 128 rows; 144 KB dynamic LDS -> 1 block/CU, 8 waves
    mega2<<<dim3(256), 512, 147456, stream>>>(x, W1, W2, W3, fc1_b, fc2_b, out_b, out);
}

// Round 9
// 217.372 us; speedup vs baseline: 1.0845x; 1.0845x over previous
//
#include <hip/hip_runtime.h>

typedef unsigned short ushort_t;
typedef __attribute__((ext_vector_type(8))) short bf16x8;     // 8 bf16 in 4 VGPRs
typedef __attribute__((ext_vector_type(4))) float f32x4;
typedef __attribute__((ext_vector_type(16))) float f32x16;

__device__ __forceinline__ unsigned short f2bf(float f) {
    union { float f; unsigned u; } v; v.f = f;
    unsigned r = v.u + 0x7FFFu + ((v.u >> 16) & 1u);   // RNE
    return (unsigned short)(r >> 16);
}

// ================= weight prep, fragment-major =================
// B-fragment layout for v_mfma_f32_32x32x16_bf16: lane = khalf*32 + r32 holds
// W[ngrp*32 + r32][kseg*16 + khalf*8 .. +8).  Stored as
//   Wf[(ngrp*KSEGS + kseg)*512 + lane*8 + e]
// so a fragment load is base + lane*16B -> fully coalesced buffer_load_dwordx4.
// W1eff folds the 3x3 conv into fc1 (p indexes the 28x28 input, zero-padded to 832).
__global__ __launch_bounds__(256) void prep_w(const float* __restrict__ fc1_w,
                                              const float* __restrict__ cw,
                                              const float* __restrict__ fc2_w,
                                              const float* __restrict__ out_w,
                                              ushort_t* __restrict__ W1,
                                              ushort_t* __restrict__ W2,
                                              ushort_t* __restrict__ W3) {
    const int idx = blockIdx.x * 256 + threadIdx.x;
    if (idx < 512 * 832) {
        int n = idx / 832, p = idx % 832;
        float acc = 0.f;
        if (p < 784) {
            int pr = p / 28, pc = p % 28;
#pragma unroll
            for (int dr = 0; dr < 3; ++dr) {
                int r = pr - dr;
                if (r < 0 || r >= 26) continue;
#pragma unroll
                for (int dc = 0; dc < 3; ++dc) {
                    int col = pc - dc;
                    if (col < 0 || col >= 26) continue;
                    acc += cw[dr * 3 + dc] * fc1_w[n * 676 + r * 26 + col];
                }
            }
        }
        const int ngrp = n >> 5, r = n & 31;
        const int kfrag = p >> 4, c = p & 15;
        const int lane = (c >> 3) * 32 + r;
        W1[((size_t)ngrp * 52 + kfrag) * 512 + lane * 8 + (c & 7)] = f2bf(acc);
    }
    if (idx < 512 * 512) {
        int n = idx >> 9, p = idx & 511;
        const int ngrp = n >> 5, r = n & 31;
        const int kfrag = p >> 4, c = p & 15;
        const int lane = (c >> 3) * 32 + r;
        W2[((size_t)ngrp * 32 + kfrag) * 512 + lane * 8 + (c & 7)] = f2bf(fc2_w[idx]);
    }
    if (idx < 16 * 512)  W3[idx] = (idx < 10 * 512) ? f2bf(out_w[idx]) : (ushort_t)0;
}

// ================= fully-fused network, v3 =================
// 256 blocks x 128 batch rows, 512 threads (8 waves), 1 block/CU (144KB LDS).
// W fragments are pre-laid-out coalesced (see prep_w) and read straight from global
// (L2-resident, 1KB/instr). x: nontemporal fp32 loads -> bf16 -> 2x8KB double-buffered
// LDS (ONE barrier per K-step). h1/h2 [128][512] in 128KB LDS; head stores direct.
__global__ __launch_bounds__(512, 2) void mega3(const float* __restrict__ x,
                                                const ushort_t* __restrict__ W1,
                                                const ushort_t* __restrict__ W2,
                                                const ushort_t* __restrict__ W3,
                                                const float* __restrict__ b1,
                                                const float* __restrict__ b2,
                                                const float* __restrict__ ob,
                                                float* __restrict__ out) {
    extern __shared__ ushort_t smem[];
    ushort_t* xs = smem;                 // [2][64][64]  16 KB  x double-buffer (seg-swizzled)
    ushort_t* hs = smem + 8192;          // [128][512]  128 KB  h1 / h2 tile

    const int tid = threadIdx.x;
    const int wave = tid >> 6, lane = tid & 63;
    const int r32 = lane & 31, khalf = lane >> 5;
    const int xrow = tid >> 3, xoct = tid & 7;          // x staging: 64 rows x 8 octs
    const int m0 = blockIdx.x * 128;

    f32x16 acc[2][2][2];                                // [mh][i][j]
#pragma unroll
    for (int a = 0; a < 2; ++a)
#pragma unroll
        for (int i = 0; i < 2; ++i)
#pragma unroll
            for (int j = 0; j < 2; ++j)
#pragma unroll
                for (int e = 0; e < 16; ++e) acc[a][i][j][e] = 0.f;

    // ---- x prefetch (nontemporal fp32), one K-step ahead ----
    f32x4 xv0[2], xv1[2];
    auto load_x = [&](int ks) {
        const int gc = ks * 64 + xoct * 8;
#pragma unroll
        for (int mh = 0; mh < 2; ++mh) {
            if (gc < 784) {
                const f32x4* p = (const f32x4*)&x[(size_t)(m0 + mh * 64 + xrow) * 784 + gc];
                xv0[mh] = __builtin_nontemporal_load(p);
                xv1[mh] = __builtin_nontemporal_load(p + 1);
            } else {
                xv0[mh] = (f32x4){0.f, 0.f, 0.f, 0.f};
                xv1[mh] = (f32x4){0.f, 0.f, 0.f, 0.f};
            }
        }
    };
    auto store_x = [&](int buf) {
#pragma unroll
        for (int mh = 0; mh < 2; ++mh) {
            bf16x8 xv;
            xv[0] = (short)f2bf(xv0[mh].x); xv[1] = (short)f2bf(xv0[mh].y);
            xv[2] = (short)f2bf(xv0[mh].z); xv[3] = (short)f2bf(xv0[mh].w);
            xv[4] = (short)f2bf(xv1[mh].x); xv[5] = (short)f2bf(xv1[mh].y);
            xv[6] = (short)f2bf(xv1[mh].z); xv[7] = (short)f2bf(xv1[mh].w);
            *(bf16x8*)&xs[buf * 8192 + mh * 4096 + xrow * 64 + ((xoct ^ (xrow & 7)) * 8)] = xv;
        }
    };

    load_x(0);
    store_x(0);
    __syncthreads();

    // ---------------- phase 1: K = 832, 13 steps of BK=64, 1 barrier/step ----------------
    for (int ks = 0; ks < 13; ++ks) {
        if (ks < 12) load_x(ks + 1);                    // issue next x loads under the MFMAs
        const int buf = ks & 1;
#pragma unroll
        for (int ksub = 0; ksub < 4; ++ksub) {
            const int kfrag = ks * 4 + ksub;
            bf16x8 bw[2], af[2][2];
#pragma unroll
            for (int j = 0; j < 2; ++j)                 // coalesced fragment load (1KB/wave)
                bw[j] = *(const bf16x8*)&W1[((size_t)(wave * 2 + j) * 52 + kfrag) * 512 + lane * 8];
            const int q = 2 * ksub + khalf;
#pragma unroll
            for (int mh = 0; mh < 2; ++mh)
#pragma unroll
                for (int i = 0; i < 2; ++i) {
                    const int mr = i * 32 + r32;
                    af[mh][i] = *(const bf16x8*)&xs[buf * 8192 + mh * 4096 + mr * 64 + ((q ^ (mr & 7)) * 8)];
                }
#pragma unroll
            for (int mh = 0; mh < 2; ++mh)
#pragma unroll
                for (int i = 0; i < 2; ++i)
#pragma unroll
                    for (int j = 0; j < 2; ++j)
                        acc[mh][i][j] = __builtin_amdgcn_mfma_f32_32x32x16_bf16(af[mh][i], bw[j], acc[mh][i][j], 0, 0, 0);
        }
        if (ks < 12) {
            store_x(1 - buf);                           // other buffer: safe while peers read buf
            __syncthreads();
        }
    }

    // ---- h1 = relu(acc + b1) -> hs (A-layout, seg' = seg ^ (m&7)) ----
    __syncthreads();
#pragma unroll
    for (int j = 0; j < 2; ++j) {
        const int n = wave * 64 + j * 32 + r32;
        const float bb = b1[n];
        const int nseg = n >> 3, nrem = n & 7;
#pragma unroll
        for (int mh = 0; mh < 2; ++mh)
#pragma unroll
            for (int i = 0; i < 2; ++i)
#pragma unroll
                for (int reg = 0; reg < 16; ++reg) {
                    const int m = mh * 64 + i * 32 + 4 * khalf + (reg & 3) + 8 * (reg >> 2);
                    hs[m * 512 + ((nseg ^ (m & 7)) * 8) + nrem] = f2bf(fmaxf(acc[mh][i][j][reg] + bb, 0.f));
                }
    }
#pragma unroll
    for (int a = 0; a < 2; ++a)
#pragma unroll
        for (int i = 0; i < 2; ++i)
#pragma unroll
            for (int j = 0; j < 2; ++j)
#pragma unroll
                for (int e = 0; e < 16; ++e) acc[a][i][j][e] = 0.f;
    __syncthreads();

    // ---------------- phase 2: K = 512, 8 steps of BK=64, no barriers ----------------
    for (int ks = 0; ks < 8; ++ks) {
#pragma unroll
        for (int ksub = 0; ksub < 4; ++ksub) {
            const int kfrag = ks * 4 + ksub;
            bf16x8 bw[2], af[2][2];
#pragma unroll
            for (int j = 0; j < 2; ++j)
                bw[j] = *(const bf16x8*)&W2[((size_t)(wave * 2 + j) * 32 + kfrag) * 512 + lane * 8];
            const int hq = ks * 8 + 2 * ksub + khalf;   // 16B-seg index within hs row (0..63)
#pragma unroll
            for (int mh = 0; mh < 2; ++mh)
#pragma unroll
                for (int i = 0; i < 2; ++i) {
                    const int m = mh * 64 + i * 32 + r32;
                    af[mh][i] = *(const bf16x8*)&hs[m * 512 + ((hq ^ (m & 7)) * 8)];
                }
#pragma unroll
            for (int mh = 0; mh < 2; ++mh)
#pragma unroll
                for (int i = 0; i < 2; ++i)
#pragma unroll
                    for (int j = 0; j < 2; ++j)
                        acc[mh][i][j] = __builtin_amdgcn_mfma_f32_32x32x16_bf16(af[mh][i], bw[j], acc[mh][i][j], 0, 0, 0);
        }
    }
    __syncthreads();                                    // all hs(h1) reads done

    // ---- h2 = relu(acc + b2) -> hs ----
#pragma unroll
    for (int j = 0; j < 2; ++j) {
        const int n = wave * 64 + j * 32 + r32;
        const float bb = b2[n];
        const int nseg = n >> 3, nrem = n & 7;
#pragma unroll
        for (int mh = 0; mh < 2; ++mh)
#pragma unroll
            for (int i = 0; i < 2; ++i)
#pragma unroll
                for (int reg = 0; reg < 16; ++reg) {
                    const int m = mh * 64 + i * 32 + 4 * khalf + (reg & 3) + 8 * (reg >> 2);
                    hs[m * 512 + ((nseg ^ (m & 7)) * 8) + nrem] = f2bf(fmaxf(acc[mh][i][j][reg] + bb, 0.f));
                }
    }
    __syncthreads();

    // ---------------- head: wave w -> rows [16w,16w+16), K=512, direct stores ----------------
    {
        const int quad = lane >> 4, l16 = lane & 15;
        const int row = wave * 16 + l16;
        f32x4 hacc = {0.f, 0.f, 0.f, 0.f};
#pragma unroll
        for (int ks = 0; ks < 16; ++ks) {
            const int seg = 4 * ks + quad;
            const bf16x8 a = *(const bf16x8*)&hs[row * 512 + ((seg ^ (row & 7)) * 8)];
            const bf16x8 b = *(const bf16x8*)&W3[l16 * 512 + ks * 32 + quad * 8];
            hacc = __builtin_amdgcn_mfma_f32_16x16x32_bf16(a, b, hacc, 0, 0, 0);
        }
        if (l16 < 10) {
            const float bb = ob[l16];
#pragma unroll
            for (int r = 0; r < 4; ++r)
                out[(size_t)(m0 + wave * 16 + quad * 4 + r) * 10 + l16] = hacc[r] + bb;
        }
    }
}

extern "C" void kernel_launch(void* const* d_in, const int* in_sizes, int n_in,
                              void* d_out, int out_size, void* d_ws, size_t ws_size,
                              hipStream_t stream) {
    const float* x      = (const float*)d_in[0];
    const float* conv_w = (const float*)d_in[1];
    const float* fc1_w  = (const float*)d_in[2];
    const float* fc1_b  = (const float*)d_in[3];
    const float* fc2_w  = (const float*)d_in[4];
    const float* fc2_b  = (const float*)d_in[5];
    const float* out_w  = (const float*)d_in[6];
    const float* out_b  = (const float*)d_in[7];
    float* out = (float*)d_out;

    // workspace: W1f | W2f | W3 (≈1.4 MB total), fragment-major layouts
    ushort_t* W1 = (ushort_t*)d_ws;                    // 512*832
    ushort_t* W2 = W1 + 512 * 832;                     // 512*512
    ushort_t* W3 = W2 + 512 * 512;                     // 16*512

    prep_w<<<dim3(1664), 256, 0, stream>>>(fc1_w, conv_w, fc2_w, out_w, W1, W2, W3);

    // 256 blocks x 128 rows; 144 KB dynamic LDS -> 1 block/CU, 8 waves
    mega3<<<dim3(256), 512, 147456, stream>>>(x, W1, W2, W3, fc1_b, fc2_b, out_b, out);
}

// Round 10
// 216.115 us; speedup vs baseline: 1.0908x; 1.0058x over previous
//
#include <hip/hip_runtime.h>

typedef unsigned short ushort_t;
typedef __attribute__((ext_vector_type(8))) short bf16x8;     // 8 bf16 in 4 VGPRs
typedef __attribute__((ext_vector_type(4))) float f32x4;
typedef __attribute__((ext_vector_type(16))) float f32x16;

__device__ __forceinline__ unsigned short f2bf(float f) {
    union { float f; unsigned u; } v; v.f = f;
    unsigned r = v.u + 0x7FFFu + ((v.u >> 16) & 1u);   // RNE
    return (unsigned short)(r >> 16);
}

// ================= weight prep, fragment-major, coalesced writes =================
// B-fragment layout for v_mfma_f32_32x32x16_bf16: lane = khalf*32 + r32 holds
// W[ngrp*32 + r32][kfrag*16 + khalf*8 .. +8).  Stored as
//   Wf[(ngrp*KFRAGS + kfrag)*512 + lane*8 + e]
// Threads index the OUTPUT (coalesced stores); the gathered reads hit L2.
// W1eff folds the 3x3 conv into fc1 (p indexes the 28x28 input, zero-padded to 832).
__global__ __launch_bounds__(256) void prep_w(const float* __restrict__ fc1_w,
                                              const float* __restrict__ cw,
                                              const float* __restrict__ fc2_w,
                                              const float* __restrict__ out_w,
                                              ushort_t* __restrict__ W1,
                                              ushort_t* __restrict__ W2,
                                              ushort_t* __restrict__ W3) {
    const int idx = blockIdx.x * 256 + threadIdx.x;
    // ---- W1f: 16 ngrps x 52 kfrags x 512 = 425984 elements ----
    if (idx < 425984) {
        const int ngrp = idx / 26624;              // 52*512
        const int kfrag = (idx % 26624) >> 9;
        const int li = idx & 511;
        const int lane = li >> 3, e = li & 7;
        const int n = ngrp * 32 + (lane & 31);
        const int p = kfrag * 16 + (lane >> 5) * 8 + e;
        float acc = 0.f;
        if (p < 784) {
            const int pr = p / 28, pc = p % 28;
#pragma unroll
            for (int dr = 0; dr < 3; ++dr) {
                const int r = pr - dr;
                if (r < 0 || r >= 26) continue;
#pragma unroll
                for (int dc = 0; dc < 3; ++dc) {
                    const int col = pc - dc;
                    if (col < 0 || col >= 26) continue;
                    acc += cw[dr * 3 + dc] * fc1_w[n * 676 + r * 26 + col];
                }
            }
        }
        W1[idx] = f2bf(acc);
    }
    // ---- W2f: 16 ngrps x 32 kfrags x 512 = 262144 ----
    if (idx < 262144) {
        const int ngrp = idx / 16384;              // 32*512
        const int kfrag = (idx % 16384) >> 9;
        const int li = idx & 511;
        const int lane = li >> 3, e = li & 7;
        const int n = ngrp * 32 + (lane & 31);
        const int p = kfrag * 16 + (lane >> 5) * 8 + e;
        W2[idx] = f2bf(fc2_w[n * 512 + p]);
    }
    if (idx < 16 * 512)  W3[idx] = (idx < 10 * 512) ? f2bf(out_w[idx]) : (ushort_t)0;
}

// ================= fully-fused network, v4: 16 waves/block =================
// 256 blocks x 128 batch rows, 1024 threads (16 waves) -> 4 waves/SIMD (2x mega3).
// Wave w owns n-group w (n = w*32 + r32): per ksub ONE coalesced W-fragment load + 4 MFMAs.
// x: nontemporal fp32 -> bf16 -> double-buffered 16KB LDS; buffer B aliases the first
// 16KB of hs (unwritten until phase1 ends). h1/h2 [128][512] in 128KB LDS. 144KB total.
__global__ __launch_bounds__(1024, 4) void mega4(const float* __restrict__ x,
                                                 const ushort_t* __restrict__ W1,
                                                 const ushort_t* __restrict__ W2,
                                                 const ushort_t* __restrict__ W3,
                                                 const float* __restrict__ b1,
                                                 const float* __restrict__ b2,
                                                 const float* __restrict__ ob,
                                                 float* __restrict__ out) {
    extern __shared__ ushort_t smem[];
    ushort_t* xs0 = smem;                // [128][64]  16 KB  x buffer A (seg-swizzled)
    ushort_t* hs  = smem + 8192;         // [128][512] 128 KB h1/h2 tile; first 16KB = x buffer B

    const int tid = threadIdx.x;
    const int wave = tid >> 6, lane = tid & 63;
    const int r32 = lane & 31, khalf = lane >> 5;
    const int xrow = tid >> 3, xoct = tid & 7;          // x staging: 128 rows x 8 octs
    const int m0 = blockIdx.x * 128;

    f32x16 acc[2][2];                                   // [mh][i], n fixed = wave*32 + r32
#pragma unroll
    for (int a = 0; a < 2; ++a)
#pragma unroll
        for (int i = 0; i < 2; ++i)
#pragma unroll
            for (int e = 0; e < 16; ++e) acc[a][i][e] = 0.f;

    // ---- x prefetch (nontemporal fp32), one K-step ahead; 1 row-segment / thread ----
    f32x4 xv0, xv1;
    auto load_x = [&](int ks) {
        const int gc = ks * 64 + xoct * 8;
        if (gc < 784) {
            const f32x4* p = (const f32x4*)&x[(size_t)(m0 + xrow) * 784 + gc];
            xv0 = __builtin_nontemporal_load(p);
            xv1 = __builtin_nontemporal_load(p + 1);
        } else {
            xv0 = (f32x4){0.f, 0.f, 0.f, 0.f};
            xv1 = (f32x4){0.f, 0.f, 0.f, 0.f};
        }
    };
    auto store_x = [&](ushort_t* buf) {
        bf16x8 xv;
        xv[0] = (short)f2bf(xv0.x); xv[1] = (short)f2bf(xv0.y);
        xv[2] = (short)f2bf(xv0.z); xv[3] = (short)f2bf(xv0.w);
        xv[4] = (short)f2bf(xv1.x); xv[5] = (short)f2bf(xv1.y);
        xv[6] = (short)f2bf(xv1.z); xv[7] = (short)f2bf(xv1.w);
        *(bf16x8*)&buf[xrow * 64 + ((xoct ^ (xrow & 7)) * 8)] = xv;
    };

    load_x(0);
    store_x(xs0);
    __syncthreads();

    // ---------------- phase 1: K = 832, 13 steps of BK=64, 1 barrier/step ----------------
    for (int ks = 0; ks < 13; ++ks) {
        if (ks < 12) load_x(ks + 1);                    // next x loads fly under the MFMAs
        const ushort_t* bufp = (ks & 1) ? hs : xs0;
#pragma unroll
        for (int ksub = 0; ksub < 4; ++ksub) {
            const int kfrag = ks * 4 + ksub;
            // ONE coalesced 1KB fragment load per wave (L2-resident)
            const bf16x8 bw = *(const bf16x8*)&W1[((size_t)wave * 52 + kfrag) * 512 + lane * 8];
            const int q = 2 * ksub + khalf;
            bf16x8 af[2][2];
#pragma unroll
            for (int mh = 0; mh < 2; ++mh)
#pragma unroll
                for (int i = 0; i < 2; ++i) {
                    const int mr = mh * 64 + i * 32 + r32;
                    af[mh][i] = *(const bf16x8*)&bufp[mr * 64 + ((q ^ (mr & 7)) * 8)];
                }
#pragma unroll
            for (int mh = 0; mh < 2; ++mh)
#pragma unroll
                for (int i = 0; i < 2; ++i)
                    acc[mh][i] = __builtin_amdgcn_mfma_f32_32x32x16_bf16(af[mh][i], bw, acc[mh][i], 0, 0, 0);
        }
        if (ks < 12) {
            store_x((ks & 1) ? xs0 : hs);               // fill the other buffer
            __syncthreads();
        }
    }
    __syncthreads();

    // ---- h1 = relu(acc + b1) -> hs (A-layout, seg' = seg ^ (m&7)); col n = wave*32+r32 ----
    {
        const int n = wave * 32 + r32;
        const float bb = b1[n];
        const int nseg = n >> 3, nrem = n & 7;
#pragma unroll
        for (int mh = 0; mh < 2; ++mh)
#pragma unroll
            for (int i = 0; i < 2; ++i)
#pragma unroll
                for (int reg = 0; reg < 16; ++reg) {
                    const int m = mh * 64 + i * 32 + 4 * khalf + (reg & 3) + 8 * (reg >> 2);
                    hs[m * 512 + ((nseg ^ (m & 7)) * 8) + nrem] = f2bf(fmaxf(acc[mh][i][reg] + bb, 0.f));
                }
    }
#pragma unroll
    for (int a = 0; a < 2; ++a)
#pragma unroll
        for (int i = 0; i < 2; ++i)
#pragma unroll
            for (int e = 0; e < 16; ++e) acc[a][i][e] = 0.f;
    __syncthreads();

    // ---------------- phase 2: K = 512, 8 steps of BK=64, no barriers ----------------
    for (int ks = 0; ks < 8; ++ks) {
#pragma unroll
        for (int ksub = 0; ksub < 4; ++ksub) {
            const int kfrag = ks * 4 + ksub;
            const bf16x8 bw = *(const bf16x8*)&W2[((size_t)wave * 32 + kfrag) * 512 + lane * 8];
            const int hq = ks * 8 + 2 * ksub + khalf;   // 16B-seg index within hs row (0..63)
            bf16x8 af[2][2];
#pragma unroll
            for (int mh = 0; mh < 2; ++mh)
#pragma unroll
                for (int i = 0; i < 2; ++i) {
                    const int m = mh * 64 + i * 32 + r32;
                    af[mh][i] = *(const bf16x8*)&hs[m * 512 + ((hq ^ (m & 7)) * 8)];
                }
#pragma unroll
            for (int mh = 0; mh < 2; ++mh)
#pragma unroll
                for (int i = 0; i < 2; ++i)
                    acc[mh][i] = __builtin_amdgcn_mfma_f32_32x32x16_bf16(af[mh][i], bw, acc[mh][i], 0, 0, 0);
        }
    }
    __syncthreads();                                    // all hs(h1) reads done

    // ---- h2 = relu(acc + b2) -> hs ----
    {
        const int n = wave * 32 + r32;
        const float bb = b2[n];
        const int nseg = n >> 3, nrem = n & 7;
#pragma unroll
        for (int mh = 0; mh < 2; ++mh)
#pragma unroll
            for (int i = 0; i < 2; ++i)
#pragma unroll
                for (int reg = 0; reg < 16; ++reg) {
                    const int m = mh * 64 + i * 32 + 4 * khalf + (reg & 3) + 8 * (reg >> 2);
                    hs[m * 512 + ((nseg ^ (m & 7)) * 8) + nrem] = f2bf(fmaxf(acc[mh][i][reg] + bb, 0.f));
                }
    }
    __syncthreads();

    // ---------------- head: waves 0..7 -> 16 rows each, K=512, direct stores ----------------
    if (wave < 8) {
        const int quad = lane >> 4, l16 = lane & 15;
        const int row = wave * 16 + l16;
        f32x4 hacc = {0.f, 0.f, 0.f, 0.f};
#pragma unroll
        for (int ks = 0; ks < 16; ++ks) {
            const int seg = 4 * ks + quad;
            const bf16x8 a = *(const bf16x8*)&hs[row * 512 + ((seg ^ (row & 7)) * 8)];
            const bf16x8 b = *(const bf16x8*)&W3[l16 * 512 + ks * 32 + quad * 8];
            hacc = __builtin_amdgcn_mfma_f32_16x16x32_bf16(a, b, hacc, 0, 0, 0);
        }
        if (l16 < 10) {
            const float bb = ob[l16];
#pragma unroll
            for (int r = 0; r < 4; ++r)
                out[(size_t)(m0 + wave * 16 + quad * 4 + r) * 10 + l16] = hacc[r] + bb;
        }
    }
}

extern "C" void kernel_launch(void* const* d_in, const int* in_sizes, int n_in,
                              void* d_out, int out_size, void* d_ws, size_t ws_size,
                              hipStream_t stream) {
    const float* x      = (const float*)d_in[0];
    const float* conv_w = (const float*)d_in[1];
    const float* fc1_w  = (const float*)d_in[2];
    const float* fc1_b  = (const float*)d_in[3];
    const float* fc2_w  = (const float*)d_in[4];
    const float* fc2_b  = (const float*)d_in[5];
    const float* out_w  = (const float*)d_in[6];
    const float* out_b  = (const float*)d_in[7];
    float* out = (float*)d_out;

    // workspace: W1f | W2f | W3 (≈1.4 MB total), fragment-major layouts
    ushort_t* W1 = (ushort_t*)d_ws;                    // 16*52*512
    ushort_t* W2 = W1 + 425984;                        // 16*32*512
    ushort_t* W3 = W2 + 262144;                        // 16*512

    prep_w<<<dim3(1664), 256, 0, stream>>>(fc1_w, conv_w, fc2_w, out_w, W1, W2, W3);

    // 256 blocks x 128 rows; 1024 threads (16 waves); 144 KB dynamic LDS -> 1 block/CU
    mega4<<<dim3(256), 1024, 147456, stream>>>(x, W1, W2, W3, fc1_b, fc2_b, out_b, out);
}